// Round 2
// baseline (16785.251 us; speedup 1.0000x reference)
//
#include <hip/hip_runtime.h>
#include <hip/hip_bf16.h>
#include <math.h>

// ---------------- problem dims ----------------
#define BB      32
#define LTOK    196
#define DMODEL  384
#define DINNER  768
#define DSTATE  16
#define DTRANK  24
#define DCONV   4
#define PROJW   (DTRANK + 2*DSTATE)   // 56
#define NTOK    (BB*LTOK)             // 6272
#define NCLS    1000
#define EPS     1e-5f

// ---------------- GEMM: C[M,N] = A[M,K] * B[N,K]^T  (+bias +rowbias +act) ----
#define GBM 128
#define GBN 64
#define GBK 16

__global__ __launch_bounds__(256) void gemm_nt(
    const float* __restrict__ A, int lda,
    const float* __restrict__ B, int ldb,
    float* __restrict__ C, int ldc,
    int M, int N, int K,
    const float* __restrict__ bias,     // [N] or null
    const float* __restrict__ rowbias,  // [LTOK*N] indexed by (m%LTOK) or null
    int act)                            // 0=none, 1=softplus
{
    __shared__ float As[GBK][GBM + 4];
    __shared__ float Bs[GBK][GBN + 4];
    const int t  = threadIdx.x;
    const int kk = t & 15;
    const int r  = t >> 4;       // 0..15
    const int bm = blockIdx.x * GBM;
    const int bn = blockIdx.y * GBN;
    const int tx = t & 15;       // n-group
    const int ty = t >> 4;       // m-group

    float acc[8][4];
    #pragma unroll
    for (int i = 0; i < 8; i++)
        #pragma unroll
        for (int j = 0; j < 4; j++) acc[i][j] = 0.f;

    for (int k0 = 0; k0 < K; k0 += GBK) {
        #pragma unroll
        for (int i = 0; i < 8; i++) {
            int m = r + i * 16;
            float v = 0.f;
            if (bm + m < M && k0 + kk < K) v = A[(size_t)(bm + m) * lda + k0 + kk];
            As[kk][m] = v;
        }
        #pragma unroll
        for (int i = 0; i < 4; i++) {
            int n = r + i * 16;
            float v = 0.f;
            if (bn + n < N && k0 + kk < K) v = B[(size_t)(bn + n) * ldb + k0 + kk];
            Bs[kk][n] = v;
        }
        __syncthreads();
        #pragma unroll
        for (int k = 0; k < GBK; k++) {
            float4 a0 = *(const float4*)&As[k][ty * 8];
            float4 a1 = *(const float4*)&As[k][ty * 8 + 4];
            float4 b0 = *(const float4*)&Bs[k][tx * 4];
            float am[8] = {a0.x, a0.y, a0.z, a0.w, a1.x, a1.y, a1.z, a1.w};
            float bv[4] = {b0.x, b0.y, b0.z, b0.w};
            #pragma unroll
            for (int i = 0; i < 8; i++)
                #pragma unroll
                for (int j = 0; j < 4; j++)
                    acc[i][j] += am[i] * bv[j];
        }
        __syncthreads();
    }

    #pragma unroll
    for (int i = 0; i < 8; i++) {
        int m = bm + ty * 8 + i;
        if (m >= M) continue;
        int lrow = m % LTOK;
        #pragma unroll
        for (int j = 0; j < 4; j++) {
            int n = bn + tx * 4 + j;
            if (n >= N) continue;
            float v = acc[i][j];
            if (bias)    v += bias[n];
            if (rowbias) v += rowbias[(size_t)lrow * N + n];
            if (act == 1) v = (v > 20.f) ? v : logf(1.f + __expf(v));
            C[(size_t)m * ldc + n] = v;
        }
    }
}

// ---------------- im2col for patch embed ----------------
__global__ void im2col_kernel(const float* __restrict__ x, float* __restrict__ col)
{
    int idx = blockIdx.x * 256 + threadIdx.x;        // over NTOK*768
    if (idx >= NTOK * 768) return;
    int k = idx % 768;
    int m = idx / 768;
    int b = m / LTOK, l = m % LTOK;
    int ph = l / 14, pw = l % 14;
    int c = k / 256, rr = k % 256;
    int i = rr / 16, j = rr % 16;
    col[idx] = x[(((size_t)b * 3 + c) * 224 + ph * 16 + i) * 224 + pw * 16 + j];
}

// ---------------- fused residual-add + LayerNorm (one wave per token) -------
__global__ __launch_bounds__(64) void add_ln_kernel(
    float* __restrict__ residual, const float* __restrict__ hidden,
    const float* __restrict__ w, const float* __restrict__ b,
    float* __restrict__ xln)
{
    const int token = blockIdx.x;
    const int lane  = threadIdx.x;
    const size_t base = (size_t)token * DMODEL;
    float v[6];
    float sum = 0.f;
    #pragma unroll
    for (int i = 0; i < 6; i++) {
        int d = lane + i * 64;
        float r = residual[base + d] + hidden[base + d];
        v[i] = r;
        sum += r;
    }
    #pragma unroll
    for (int off = 32; off > 0; off >>= 1) sum += __shfl_xor(sum, off);
    float mu = sum * (1.f / DMODEL);
    float var = 0.f;
    #pragma unroll
    for (int i = 0; i < 6; i++) { float c = v[i] - mu; var += c * c; }
    #pragma unroll
    for (int off = 32; off > 0; off >>= 1) var += __shfl_xor(var, off);
    var *= (1.f / DMODEL);
    float rstd = rsqrtf(var + EPS);
    #pragma unroll
    for (int i = 0; i < 6; i++) {
        int d = lane + i * 64;
        residual[base + d] = v[i];
        xln[base + d] = (v[i] - mu) * rstd * w[d] + b[d];
    }
}

// ---------------- depthwise causal conv (k=4) + SiLU ----------------
__global__ __launch_bounds__(256) void conv_silu_kernel(
    const float* __restrict__ xz,      // [NTOK,1536]; xc = cols 0..767
    const float* __restrict__ cw,      // [768,4]
    const float* __restrict__ cb,      // [768]
    float* __restrict__ out)           // [NTOK,768]
{
    int idx = blockIdx.x * 256 + threadIdx.x;
    if (idx >= NTOK * DINNER) return;
    int e = idx % DINNER;
    int m = idx / DINNER;          // token index b*LTOK + t
    int b = m / LTOK, tpos = m % LTOK;
    float4 w4 = ((const float4*)cw)[e];
    float wv[4] = {w4.x, w4.y, w4.z, w4.w};
    float acc = cb[e];
    #pragma unroll
    for (int tau = 0; tau < DCONV; tau++) {
        int l = tpos - (DCONV - 1) + tau;
        if (l >= 0)
            acc += wv[tau] * xz[((size_t)(b * LTOK + l)) * (2 * DINNER) + e];
    }
    out[idx] = acc / (1.f + __expf(-acc)) ;   // silu
}

// ---------------- selective scan (thread owns (b,d), 16 states in regs) -----
__global__ __launch_bounds__(256) void scan_kernel(
    const float* __restrict__ delta,   // [NTOK,768]
    const float* __restrict__ u,       // [NTOK,768] (conv+silu output)
    const float* __restrict__ proj,    // [NTOK,56]  (dt|B|C)
    const float* __restrict__ xz,      // [NTOK,1536] (z = cols 768..1535)
    const float* __restrict__ A_log,   // [768,16]
    const float* __restrict__ Dp,      // [768]
    float* __restrict__ y)             // [NTOK,768] (may alias delta)
{
    const int b = blockIdx.x;                       // 0..31
    const int d = blockIdx.y * 256 + threadIdx.x;   // 0..767
    float Arow[DSTATE];
    #pragma unroll
    for (int n = 0; n < DSTATE; n++) Arow[n] = -__expf(A_log[(size_t)d * DSTATE + n]);
    const float ddp = Dp[d];
    float h[DSTATE];
    #pragma unroll
    for (int n = 0; n < DSTATE; n++) h[n] = 0.f;

    for (int l = 0; l < LTOK; l++) {
        const size_t row = (size_t)b * LTOK + l;
        const float dt = delta[row * DINNER + d];
        const float ut = u[row * DINNER + d];
        const float* pr = proj + row * PROJW;
        const float du = dt * ut;
        float acc = 0.f;
        #pragma unroll
        for (int n = 0; n < DSTATE; n++) {
            h[n] = __expf(dt * Arow[n]) * h[n] + du * pr[DTRANK + n];
            acc += h[n] * pr[DTRANK + DSTATE + n];
        }
        float zz = xz[row * (2 * DINNER) + DINNER + d];
        float g  = zz / (1.f + __expf(-zz));
        y[row * DINNER + d] = (acc + ut * ddp) * g;
    }
}

// ---------------- mean pool over tokens ----------------
__global__ __launch_bounds__(256) void pool_kernel(const float* __restrict__ xln,
                                                   float* __restrict__ pooled)
{
    int idx = blockIdx.x * 256 + threadIdx.x;   // 32*384
    if (idx >= BB * DMODEL) return;
    int b = idx / DMODEL, d = idx % DMODEL;
    float s = 0.f;
    for (int l = 0; l < LTOK; l++) s += xln[((size_t)b * LTOK + l) * DMODEL + d];
    pooled[idx] = s * (1.f / LTOK);
}

// ---------------- classifier head ----------------
__global__ __launch_bounds__(256) void head_kernel(const float* __restrict__ pooled,
                                                   const float* __restrict__ hw,
                                                   const float* __restrict__ hb,
                                                   float* __restrict__ out)
{
    int idx = blockIdx.x * 256 + threadIdx.x;   // 32*1000
    if (idx >= BB * NCLS) return;
    int b = idx / NCLS, n = idx % NCLS;
    float s = hb[n];
    const float* p = pooled + (size_t)b * DMODEL;
    const float* w = hw + (size_t)n * DMODEL;
    for (int k = 0; k < DMODEL; k++) s += p[k] * w[k];
    out[idx] = s;
}

// ---------------- launcher ----------------
static inline void launch_gemm(const float* A, int lda, const float* B, int ldb,
                               float* C, int ldc, int M, int N, int K,
                               const float* bias, const float* rowbias, int act,
                               hipStream_t stream)
{
    dim3 grid((M + GBM - 1) / GBM, (N + GBN - 1) / GBN);
    gemm_nt<<<grid, 256, 0, stream>>>(A, lda, B, ldb, C, ldc, M, N, K, bias, rowbias, act);
}

extern "C" void kernel_launch(void* const* d_in, const int* in_sizes, int n_in,
                              void* d_out, int out_size, void* d_ws, size_t ws_size,
                              hipStream_t stream)
{
    const float* x       = (const float*)d_in[0];
    const float* patch_w = (const float*)d_in[1];
    const float* patch_b = (const float*)d_in[2];
    const float* pos     = (const float*)d_in[3];
    const float* W_in    = (const float*)d_in[4];
    const float* conv_w  = (const float*)d_in[5];
    const float* conv_b  = (const float*)d_in[6];
    const float* W_xp    = (const float*)d_in[7];
    const float* W_dt    = (const float*)d_in[8];
    const float* b_dt    = (const float*)d_in[9];
    const float* A_log   = (const float*)d_in[10];
    const float* D_p     = (const float*)d_in[11];
    const float* W_out   = (const float*)d_in[12];
    const float* ln_w    = (const float*)d_in[13];
    const float* ln_b    = (const float*)d_in[14];
    const float* normf_w = (const float*)d_in[15];
    const float* normf_b = (const float*)d_in[16];
    const float* head_w  = (const float*)d_in[17];
    const float* head_b  = (const float*)d_in[18];
    float* out = (float*)d_out;

    float* ws = (float*)d_ws;
    size_t off = 0;
    float* xz     = ws + off; off += (size_t)NTOK * 1536;   // also im2col staging
    float* xcv    = ws + off; off += (size_t)NTOK * DINNER;
    float* proj   = ws + off; off += (size_t)NTOK * PROJW;
    float* delta  = ws + off; off += (size_t)NTOK * DINNER;
    float* resid  = ws + off; off += (size_t)NTOK * DMODEL;
    float* hid    = ws + off; off += (size_t)NTOK * DMODEL;
    float* xln    = ws + off; off += (size_t)NTOK * DMODEL;
    float* pooled = ws + off; off += (size_t)BB * DMODEL;
    float* ybuf   = delta;   // scan runs in-place (reads delta[row,d], then writes same slot)

    hipMemsetAsync(resid, 0, (size_t)NTOK * DMODEL * sizeof(float), stream);

    // patch embed: im2col + GEMM (bias + pos-embed fused in epilogue)
    im2col_kernel<<<(NTOK * 768 + 255) / 256, 256, 0, stream>>>(x, xz);
    launch_gemm(xz, 768, patch_w, 768, hid, DMODEL, NTOK, DMODEL, 768,
                patch_b, pos, 0, stream);

    for (int l = 0; l < 24; l++) {
        add_ln_kernel<<<NTOK, 64, 0, stream>>>(resid, hid,
                                               ln_w + (size_t)l * DMODEL,
                                               ln_b + (size_t)l * DMODEL, xln);
        // in-projection: [NTOK,384] x [1536,384]^T -> [NTOK,1536]
        launch_gemm(xln, DMODEL, W_in + (size_t)l * 2 * DINNER * DMODEL, DMODEL,
                    xz, 2 * DINNER, NTOK, 2 * DINNER, DMODEL, nullptr, nullptr, 0, stream);
        // depthwise causal conv + silu
        conv_silu_kernel<<<(NTOK * DINNER + 255) / 256, 256, 0, stream>>>(
            xz, conv_w + (size_t)l * DINNER * DCONV, conv_b + (size_t)l * DINNER, xcv);
        // x-projection: [NTOK,768] x [56,768]^T -> [NTOK,56]
        launch_gemm(xcv, DINNER, W_xp + (size_t)l * PROJW * DINNER, DINNER,
                    proj, PROJW, NTOK, PROJW, DINNER, nullptr, nullptr, 0, stream);
        // dt-projection + softplus: [NTOK,24] x [768,24]^T -> [NTOK,768]
        launch_gemm(proj, PROJW, W_dt + (size_t)l * DINNER * DTRANK, DTRANK,
                    delta, DINNER, NTOK, DINNER, DTRANK,
                    b_dt + (size_t)l * DINNER, nullptr, 1, stream);
        // selective scan + D skip + silu(z) gate (in-place into delta buffer)
        scan_kernel<<<dim3(BB, DINNER / 256), 256, 0, stream>>>(
            delta, xcv, proj, xz,
            A_log + (size_t)l * DINNER * DSTATE, D_p + (size_t)l * DINNER, ybuf);
        // out-projection: [NTOK,768] x [384,768]^T -> [NTOK,384]
        launch_gemm(ybuf, DINNER, W_out + (size_t)l * DMODEL * DINNER, DINNER,
                    hid, DMODEL, NTOK, DMODEL, DINNER, nullptr, nullptr, 0, stream);
    }

    // final: residual add + LN + mean pool + head
    add_ln_kernel<<<NTOK, 64, 0, stream>>>(resid, hid, normf_w, normf_b, xln);
    pool_kernel<<<(BB * DMODEL + 255) / 256, 256, 0, stream>>>(xln, pooled);
    head_kernel<<<(BB * NCLS + 255) / 256, 256, 0, stream>>>(pooled, head_w, head_b, out);
}

// Round 3
// 8163.393 us; speedup vs baseline: 2.0562x; 2.0562x over previous
//
#include <hip/hip_runtime.h>
#include <hip/hip_bf16.h>
#include <math.h>

// ---------------- problem dims ----------------
#define BB      32
#define LTOK    196
#define DMODEL  384
#define DINNER  768
#define DSTATE  16
#define DTRANK  24
#define DCONV   4
#define PROJW   (DTRANK + 2*DSTATE)   // 56
#define NTOK    (BB*LTOK)             // 6272 = 49*128
#define NCLS    1000
#define EPS     1e-5f

typedef __attribute__((ext_vector_type(8))) short short8v;
typedef __attribute__((ext_vector_type(4))) float f32x4;

static __device__ __forceinline__ ushort f2bf(float f) {
    unsigned u = __float_as_uint(f);
    unsigned r = (u + 0x7fffu + ((u >> 16) & 1u)) >> 16;   // RNE
    return (ushort)r;
}
static __device__ __forceinline__ float bf2f(ushort h) {
    unsigned u = ((unsigned)h) << 16;
    return __uint_as_float(u);
}

// ---------------- fp32 -> bf16 cast (grid-stride, vectorized) ----------------
__global__ void cast_bf16_kernel(const float* __restrict__ src,
                                 ushort* __restrict__ dst, int n4)
{
    int stride = gridDim.x * blockDim.x;
    for (int i = blockIdx.x * blockDim.x + threadIdx.x; i < n4; i += stride) {
        float4 v = ((const float4*)src)[i];
        ushort4 o;
        o.x = f2bf(v.x); o.y = f2bf(v.y); o.z = f2bf(v.z); o.w = f2bf(v.w);
        ((ushort4*)dst)[i] = o;
    }
}

// ---------------- bf16 MFMA GEMM: C[M,N] = A[M,K] * B[N,K]^T (+bias +rowbias)
// M == 6272 (exact multiple of 128), N % 128 == 0, K % 32 == 0. No bounds checks.
// 128x128 tile, 4 waves in 2x2, each wave 64x64 via 4x4 frags of 16x16x32.
__global__ __launch_bounds__(256) void gemm_mfma(
    const ushort* __restrict__ A,
    const ushort* __restrict__ B,
    float* __restrict__ C,
    int N, int K,
    const float* __restrict__ bias,     // [N] or null
    const float* __restrict__ rowbias)  // [LTOK*N] via (row%LTOK) or null
{
    __shared__ __align__(16) ushort As[128 * 40];   // 80B rows: <=2-way bank alias (free)
    __shared__ __align__(16) ushort Bs[128 * 40];
    const int t    = threadIdx.x;
    const int lane = t & 63;
    const int wave = t >> 6;
    const int wr   = wave >> 1;        // 0..1
    const int wc   = wave & 1;         // 0..1
    const int lr   = lane & 15;        // frag row/col
    const int lk   = lane >> 4;        // k-chunk 0..3
    const int bm   = blockIdx.x * 128;
    const int bn   = blockIdx.y * 128;

    f32x4 acc[4][4];
    #pragma unroll
    for (int i = 0; i < 4; i++)
        #pragma unroll
        for (int j = 0; j < 4; j++) acc[i][j] = (f32x4){0.f, 0.f, 0.f, 0.f};

    for (int k0 = 0; k0 < K; k0 += 32) {
        #pragma unroll
        for (int i = 0; i < 2; i++) {
            int c   = t + i * 256;          // 0..511 : 128 rows x 4 16B-chunks
            int row = c >> 2;
            int kc  = (c & 3) * 8;
            *(int4*)&As[row * 40 + kc] = *(const int4*)&A[(size_t)(bm + row) * K + k0 + kc];
            *(int4*)&Bs[row * 40 + kc] = *(const int4*)&B[(size_t)(bn + row) * K + k0 + kc];
        }
        __syncthreads();
        short8v af[4], bfr[4];
        #pragma unroll
        for (int mi = 0; mi < 4; mi++)
            af[mi] = *(short8v*)&As[(wr * 64 + mi * 16 + lr) * 40 + lk * 8];
        #pragma unroll
        for (int ni = 0; ni < 4; ni++)
            bfr[ni] = *(short8v*)&Bs[(wc * 64 + ni * 16 + lr) * 40 + lk * 8];
        #pragma unroll
        for (int mi = 0; mi < 4; mi++)
            #pragma unroll
            for (int ni = 0; ni < 4; ni++)
                acc[mi][ni] = __builtin_amdgcn_mfma_f32_16x16x32_bf16(
                    af[mi], bfr[ni], acc[mi][ni], 0, 0, 0);
        __syncthreads();
    }

    #pragma unroll
    for (int mi = 0; mi < 4; mi++) {
        #pragma unroll
        for (int ni = 0; ni < 4; ni++) {
            int col = bn + wc * 64 + ni * 16 + lr;
            float bv = bias ? bias[col] : 0.f;
            #pragma unroll
            for (int j = 0; j < 4; j++) {
                int row = bm + wr * 64 + mi * 16 + lk * 4 + j;
                float v = acc[mi][ni][j] + bv;
                if (rowbias) v += rowbias[(size_t)(row % LTOK) * N + col];
                C[(size_t)row * N + col] = v;
            }
        }
    }
}

// ---------------- im2col for patch embed (writes bf16) ----------------
__global__ void im2col_kernel(const float* __restrict__ x, ushort* __restrict__ col)
{
    int idx = blockIdx.x * 256 + threadIdx.x;        // over NTOK*768
    if (idx >= NTOK * 768) return;
    int k = idx % 768;
    int m = idx / 768;
    int b = m / LTOK, l = m % LTOK;
    int ph = l / 14, pw = l % 14;
    int c = k / 256, rr = k % 256;
    int i = rr / 16, j = rr % 16;
    col[idx] = f2bf(x[(((size_t)b * 3 + c) * 224 + ph * 16 + i) * 224 + pw * 16 + j]);
}

// ---------------- fused residual-add + LayerNorm (fp32 + bf16 outputs) -------
__global__ __launch_bounds__(64) void add_ln_kernel(
    float* __restrict__ residual, const float* __restrict__ hidden,
    const float* __restrict__ w, const float* __restrict__ b,
    float* __restrict__ xln, ushort* __restrict__ xln_bf)
{
    const int token = blockIdx.x;
    const int lane  = threadIdx.x;
    const size_t base = (size_t)token * DMODEL;
    float v[6];
    float sum = 0.f;
    #pragma unroll
    for (int i = 0; i < 6; i++) {
        int d = lane + i * 64;
        float r = residual[base + d] + hidden[base + d];
        v[i] = r;
        sum += r;
    }
    #pragma unroll
    for (int off = 32; off > 0; off >>= 1) sum += __shfl_xor(sum, off);
    float mu = sum * (1.f / DMODEL);
    float var = 0.f;
    #pragma unroll
    for (int i = 0; i < 6; i++) { float c = v[i] - mu; var += c * c; }
    #pragma unroll
    for (int off = 32; off > 0; off >>= 1) var += __shfl_xor(var, off);
    var *= (1.f / DMODEL);
    float rstd = rsqrtf(var + EPS);
    #pragma unroll
    for (int i = 0; i < 6; i++) {
        int d = lane + i * 64;
        residual[base + d] = v[i];
        float o = (v[i] - mu) * rstd * w[d] + b[d];
        xln[base + d]    = o;
        xln_bf[base + d] = f2bf(o);
    }
}

// ---------------- depthwise causal conv (k=4) + SiLU ----------------
__global__ __launch_bounds__(256) void conv_silu_kernel(
    const float* __restrict__ xz,      // [NTOK,1536]; xc = cols 0..767
    const float* __restrict__ cw,      // [768,4]
    const float* __restrict__ cb,      // [768]
    float* __restrict__ out)           // [NTOK,768]
{
    int idx = blockIdx.x * 256 + threadIdx.x;
    if (idx >= NTOK * DINNER) return;
    int e = idx % DINNER;
    int m = idx / DINNER;
    int b = m / LTOK, tpos = m % LTOK;
    float4 w4 = ((const float4*)cw)[e];
    float wv[4] = {w4.x, w4.y, w4.z, w4.w};
    float acc = cb[e];
    #pragma unroll
    for (int tau = 0; tau < DCONV; tau++) {
        int l = tpos - (DCONV - 1) + tau;
        if (l >= 0)
            acc += wv[tau] * xz[((size_t)(b * LTOK + l)) * (2 * DINNER) + e];
    }
    out[idx] = acc / (1.f + __expf(-acc));
}

// ---------------- fused x-proj (56 cols) + dt-proj (K=24) + softplus ---------
#define XPDT_TPB 4
__global__ __launch_bounds__(256) void xpdt_kernel(
    const float* __restrict__ xcv,    // [NTOK,768]
    const float* __restrict__ W_xp,   // [56,768]
    const float* __restrict__ W_dt,   // [768,24]
    const float* __restrict__ b_dt,   // [768]
    float* __restrict__ proj,         // [NTOK,56]
    float* __restrict__ delta)        // [NTOK,768]
{
    __shared__ float xs[XPDT_TPB][DINNER];
    __shared__ float ps[XPDT_TPB][DTRANK];
    const int t = threadIdx.x;
    const int tok0 = blockIdx.x * XPDT_TPB;

    #pragma unroll
    for (int i = 0; i < 3; i++) {                // 768 float4s total
        int u  = t + i * 256;
        int tt = u / 192;
        int kk = (u % 192) * 4;
        *(float4*)&xs[tt][kk] = *(const float4*)&xcv[(size_t)(tok0 + tt) * DINNER + kk];
    }
    __syncthreads();

    if (t < XPDT_TPB * PROJW) {                  // 224 active
        int tt = t / PROJW, c = t % PROJW;
        const float4* w = (const float4*)(W_xp + (size_t)c * DINNER);
        float s = 0.f;
        #pragma unroll 4
        for (int k = 0; k < DINNER / 4; k++) {
            float4 xv = *(const float4*)&xs[tt][k * 4];
            float4 wv = w[k];
            s += xv.x * wv.x + xv.y * wv.y + xv.z * wv.z + xv.w * wv.w;
        }
        proj[(size_t)(tok0 + tt) * PROJW + c] = s;
        if (c < DTRANK) ps[tt][c] = s;
    }
    __syncthreads();

    #pragma unroll
    for (int i = 0; i < 12; i++) {               // 4 tokens * 768 outputs
        int u  = i * 256 + t;
        int tt = u / DINNER;
        int e  = u % DINNER;
        const float4* w = (const float4*)(W_dt + (size_t)e * DTRANK);
        float s = b_dt[e];
        #pragma unroll
        for (int q = 0; q < 6; q++) {
            float4 wv = w[q];
            s += ps[tt][q * 4 + 0] * wv.x + ps[tt][q * 4 + 1] * wv.y +
                 ps[tt][q * 4 + 2] * wv.z + ps[tt][q * 4 + 3] * wv.w;
        }
        float sp = (s > 20.f) ? s : logf(1.f + __expf(s));
        delta[(size_t)(tok0 + tt) * DINNER + e] = sp;
    }
}

// ---------------- selective scan (thread owns (b,d), 16 states in regs) -----
__global__ __launch_bounds__(64) void scan_kernel(
    const float* __restrict__ delta,   // [NTOK,768]
    const float* __restrict__ u,       // [NTOK,768]
    const float* __restrict__ proj,    // [NTOK,56]  (dt|B|C)
    const float* __restrict__ xz,      // [NTOK,1536] (z = cols 768..1535)
    const float* __restrict__ A_log,   // [768,16]
    const float* __restrict__ Dp,      // [768]
    ushort* __restrict__ y)            // [NTOK,768] bf16
{
    const int b = blockIdx.x;                      // 0..31
    const int d = blockIdx.y * 64 + threadIdx.x;   // 0..767
    float Arow[DSTATE];
    #pragma unroll
    for (int n = 0; n < DSTATE; n++) Arow[n] = -__expf(A_log[(size_t)d * DSTATE + n]);
    const float ddp = Dp[d];
    float h[DSTATE];
    #pragma unroll
    for (int n = 0; n < DSTATE; n++) h[n] = 0.f;

    for (int l = 0; l < LTOK; l++) {
        const size_t row = (size_t)b * LTOK + l;
        const float dt = delta[row * DINNER + d];
        const float ut = u[row * DINNER + d];
        float Bv[DSTATE], Cv[DSTATE];
        const float4* prB = (const float4*)(proj + row * PROJW + DTRANK);
        const float4* prC = (const float4*)(proj + row * PROJW + DTRANK + DSTATE);
        #pragma unroll
        for (int q = 0; q < 4; q++) {
            float4 b4 = prB[q];
            Bv[q*4+0]=b4.x; Bv[q*4+1]=b4.y; Bv[q*4+2]=b4.z; Bv[q*4+3]=b4.w;
            float4 c4 = prC[q];
            Cv[q*4+0]=c4.x; Cv[q*4+1]=c4.y; Cv[q*4+2]=c4.z; Cv[q*4+3]=c4.w;
        }
        const float du = dt * ut;
        float acc = 0.f;
        #pragma unroll
        for (int n = 0; n < DSTATE; n++) {
            h[n] = __expf(dt * Arow[n]) * h[n] + du * Bv[n];
            acc += h[n] * Cv[n];
        }
        float zz = xz[row * (2 * DINNER) + DINNER + d];
        float g  = zz / (1.f + __expf(-zz));
        y[row * DINNER + d] = f2bf((acc + ut * ddp) * g);
    }
}

// ---------------- mean pool over tokens ----------------
__global__ __launch_bounds__(256) void pool_kernel(const float* __restrict__ xln,
                                                   float* __restrict__ pooled)
{
    int idx = blockIdx.x * 256 + threadIdx.x;   // 32*384
    if (idx >= BB * DMODEL) return;
    int b = idx / DMODEL, d = idx % DMODEL;
    float s = 0.f;
    for (int l = 0; l < LTOK; l++) s += xln[((size_t)b * LTOK + l) * DMODEL + d];
    pooled[idx] = s * (1.f / LTOK);
}

// ---------------- classifier head ----------------
__global__ __launch_bounds__(256) void head_kernel(const float* __restrict__ pooled,
                                                   const float* __restrict__ hw,
                                                   const float* __restrict__ hb,
                                                   float* __restrict__ out)
{
    int idx = blockIdx.x * 256 + threadIdx.x;   // 32*1000
    if (idx >= BB * NCLS) return;
    int b = idx / NCLS, n = idx % NCLS;
    float s = hb[n];
    const float* p = pooled + (size_t)b * DMODEL;
    const float* w = hw + (size_t)n * DMODEL;
    for (int k = 0; k < DMODEL; k++) s += p[k] * w[k];
    out[idx] = s;
}

// ---------------- launcher ----------------
extern "C" void kernel_launch(void* const* d_in, const int* in_sizes, int n_in,
                              void* d_out, int out_size, void* d_ws, size_t ws_size,
                              hipStream_t stream)
{
    const float* x       = (const float*)d_in[0];
    const float* patch_w = (const float*)d_in[1];
    const float* patch_b = (const float*)d_in[2];
    const float* pos     = (const float*)d_in[3];
    const float* W_in    = (const float*)d_in[4];
    const float* conv_w  = (const float*)d_in[5];
    const float* conv_b  = (const float*)d_in[6];
    const float* W_xp    = (const float*)d_in[7];
    const float* W_dt    = (const float*)d_in[8];
    const float* b_dt    = (const float*)d_in[9];
    const float* A_log   = (const float*)d_in[10];
    const float* D_p     = (const float*)d_in[11];
    const float* W_out   = (const float*)d_in[12];
    const float* ln_w    = (const float*)d_in[13];
    const float* ln_b    = (const float*)d_in[14];
    const float* normf_w = (const float*)d_in[15];
    const float* normf_b = (const float*)d_in[16];
    const float* head_w  = (const float*)d_in[17];
    const float* head_b  = (const float*)d_in[18];
    float* out = (float*)d_out;

    // ---- fp32 workspace ----
    float* wsf = (float*)d_ws;
    size_t off = 0;
    float* xz     = wsf + off; off += (size_t)NTOK * 1536;
    float* xcv    = wsf + off; off += (size_t)NTOK * DINNER;
    float* proj   = wsf + off; off += (size_t)NTOK * PROJW;
    float* delta  = wsf + off; off += (size_t)NTOK * DINNER;
    float* resid  = wsf + off; off += (size_t)NTOK * DMODEL;
    float* hid    = wsf + off; off += (size_t)NTOK * DMODEL;
    float* xln    = wsf + off; off += (size_t)NTOK * DMODEL;
    float* pooled = wsf + off; off += (size_t)BB * DMODEL;
    // ---- bf16 workspace (16B-aligned: fp32 total is multiple of 4 floats) ----
    ushort* wsu = (ushort*)(wsf + off);
    size_t uoff = 0;
    ushort* Win_bf    = wsu + uoff; uoff += (size_t)24 * 1536 * DMODEL;
    ushort* Wout_bf   = wsu + uoff; uoff += (size_t)24 * DMODEL * DINNER;
    ushort* patchw_bf = wsu + uoff; uoff += (size_t)DMODEL * 768;
    ushort* xln_bf    = wsu + uoff; uoff += (size_t)NTOK * DMODEL;
    ushort* y_bf      = wsu + uoff; uoff += (size_t)NTOK * DINNER;  // aliased as im2col buf
    ushort* col_bf    = y_bf;   // patch GEMM consumes before scan ever writes

    // ---- weight casts (run every call; graph-safe) ----
    cast_bf16_kernel<<<2048, 256, 0, stream>>>(W_in,    Win_bf,    24 * 1536 * DMODEL / 4);
    cast_bf16_kernel<<<2048, 256, 0, stream>>>(W_out,   Wout_bf,   24 * DMODEL * DINNER / 4);
    cast_bf16_kernel<<<256,  256, 0, stream>>>(patch_w, patchw_bf, DMODEL * 768 / 4);

    hipMemsetAsync(resid, 0, (size_t)NTOK * DMODEL * sizeof(float), stream);

    // patch embed: im2col(bf16) + MFMA GEMM (bias + pos fused)
    im2col_kernel<<<(NTOK * 768 + 255) / 256, 256, 0, stream>>>(x, col_bf);
    gemm_mfma<<<dim3(NTOK / 128, DMODEL / 128), 256, 0, stream>>>(
        col_bf, patchw_bf, hid, DMODEL, 768, patch_b, pos);

    for (int l = 0; l < 24; l++) {
        add_ln_kernel<<<NTOK, 64, 0, stream>>>(resid, hid,
                                               ln_w + (size_t)l * DMODEL,
                                               ln_b + (size_t)l * DMODEL, xln, xln_bf);
        // in-projection: [6272,384] x [1536,384]^T -> [6272,1536]
        gemm_mfma<<<dim3(NTOK / 128, 1536 / 128), 256, 0, stream>>>(
            xln_bf, Win_bf + (size_t)l * 1536 * DMODEL, xz, 1536, DMODEL, nullptr, nullptr);
        conv_silu_kernel<<<(NTOK * DINNER + 255) / 256, 256, 0, stream>>>(
            xz, conv_w + (size_t)l * DINNER * DCONV, conv_b + (size_t)l * DINNER, xcv);
        xpdt_kernel<<<NTOK / XPDT_TPB, 256, 0, stream>>>(
            xcv, W_xp + (size_t)l * PROJW * DINNER, W_dt + (size_t)l * DINNER * DTRANK,
            b_dt + (size_t)l * DINNER, proj, delta);
        scan_kernel<<<dim3(BB, DINNER / 64), 64, 0, stream>>>(
            delta, xcv, proj, xz,
            A_log + (size_t)l * DINNER * DSTATE, D_p + (size_t)l * DINNER, y_bf);
        // out-projection: [6272,768] x [384,768]^T -> [6272,384]
        gemm_mfma<<<dim3(NTOK / 128, DMODEL / 128), 256, 0, stream>>>(
            y_bf, Wout_bf + (size_t)l * DMODEL * DINNER, hid, DMODEL, DINNER, nullptr, nullptr);
    }

    add_ln_kernel<<<NTOK, 64, 0, stream>>>(resid, hid, normf_w, normf_b, xln, xln_bf);
    pool_kernel<<<(BB * DMODEL + 255) / 256, 256, 0, stream>>>(xln, pooled);
    head_kernel<<<(BB * NCLS + 255) / 256, 256, 0, stream>>>(pooled, head_w, head_b, out);
}

// Round 4
// 5566.693 us; speedup vs baseline: 3.0153x; 1.4665x over previous
//
#include <hip/hip_runtime.h>
#include <hip/hip_bf16.h>
#include <math.h>

// ---------------- problem dims ----------------
#define BB      32
#define LTOK    196
#define DMODEL  384
#define DINNER  768
#define DSTATE  16
#define DTRANK  24
#define DCONV   4
#define PROJW   64                    // padded x-proj width (56 -> 64)
#define NTOK    (BB*LTOK)             // 6272 = 49*128
#define NCLS    1000
#define EPS     1e-5f

typedef __attribute__((ext_vector_type(8))) short short8v;
typedef __attribute__((ext_vector_type(4))) float f32x4;

static __device__ __forceinline__ ushort f2bf(float f) {
    unsigned u = __float_as_uint(f);
    unsigned r = (u + 0x7fffu + ((u >> 16) & 1u)) >> 16;   // RNE
    return (ushort)r;
}
static __device__ __forceinline__ float bf2f(ushort h) {
    return __uint_as_float(((unsigned)h) << 16);
}

// ---------------- fp32 -> bf16 cast (grid-stride, vectorized) ----------------
__global__ void cast_bf16_kernel(const float* __restrict__ src,
                                 ushort* __restrict__ dst, int n4)
{
    int stride = gridDim.x * blockDim.x;
    for (int i = blockIdx.x * blockDim.x + threadIdx.x; i < n4; i += stride) {
        float4 v = ((const float4*)src)[i];
        ushort4 o;
        o.x = f2bf(v.x); o.y = f2bf(v.y); o.z = f2bf(v.z); o.w = f2bf(v.w);
        ((ushort4*)dst)[i] = o;
    }
}

// ---- W_xp [24,56,768] -> bf16 [24,64,768] (zero-padded rows) ----
__global__ void pad_wxp_kernel(const float* __restrict__ src, ushort* __restrict__ dst)
{
    int idx = blockIdx.x * 256 + threadIdx.x;
    if (idx >= 24 * 64 * 768) return;
    int c = idx % 768;
    int r = (idx / 768) & 63;
    int l = idx / (64 * 768);
    dst[idx] = (r < 56) ? f2bf(src[((size_t)l * 56 + r) * 768 + c]) : (ushort)0;
}

// ---- W_dt [24,768,24] -> bf16 [24,768,32] (zero-padded cols) ----
__global__ void pad_wdt_kernel(const float* __restrict__ src, ushort* __restrict__ dst)
{
    int idx = blockIdx.x * 256 + threadIdx.x;
    if (idx >= 24 * 768 * 32) return;
    int c = idx & 31;
    int r = (idx / 32) % 768;
    int l = idx / (768 * 32);
    dst[idx] = (c < 24) ? f2bf(src[((size_t)l * 768 + r) * 24 + c]) : (ushort)0;
}

// ---------------- bf16 MFMA GEMM: C[M,N] = A[M,K]*B[N,K]^T --------------------
// M%BM==0, N%BN==0, K%32==0. 4 waves in 2x2; wave tile (BM/2)x(BN/2).
// mode 0: Cf fp32 (+bias +rowbias +act)
// mode 1: Cbf bf16 (ld = N)
// mode 2: Cf fp32 (ld = N) AND dt-pad bf16 [M,32] (col<24 = value, 24..31 = 0)
template<int BM, int BN>
__global__ __launch_bounds__(256) void gemm_mfma(
    const ushort* __restrict__ A,
    const ushort* __restrict__ B,
    float* __restrict__ Cf, ushort* __restrict__ Cbf,
    int N, int K,
    const float* __restrict__ bias,
    const float* __restrict__ rowbias,
    int act, int mode)
{
    constexpr int MI = BM / 32;      // frags per wave in M
    constexpr int NI = BN / 32;
    __shared__ __align__(16) ushort As[BM * 40];   // 80B rows
    __shared__ __align__(16) ushort Bs[BN * 40];
    const int t    = threadIdx.x;
    const int lane = t & 63;
    const int wave = t >> 6;
    const int wr   = wave >> 1;
    const int wc   = wave & 1;
    const int lr   = lane & 15;
    const int lk   = lane >> 4;
    const int bm   = blockIdx.x * BM;
    const int bn   = blockIdx.y * BN;

    f32x4 acc[MI][NI];
    #pragma unroll
    for (int i = 0; i < MI; i++)
        #pragma unroll
        for (int j = 0; j < NI; j++) acc[i][j] = (f32x4){0.f, 0.f, 0.f, 0.f};

    for (int k0 = 0; k0 < K; k0 += 32) {
        #pragma unroll
        for (int i = 0; i < BM / 64; i++) {
            int c = t + i * 256;
            int row = c >> 2, kc = (c & 3) * 8;
            *(int4*)&As[row * 40 + kc] = *(const int4*)&A[(size_t)(bm + row) * K + k0 + kc];
        }
        #pragma unroll
        for (int i = 0; i < BN / 64; i++) {
            int c = t + i * 256;
            int row = c >> 2, kc = (c & 3) * 8;
            *(int4*)&Bs[row * 40 + kc] = *(const int4*)&B[(size_t)(bn + row) * K + k0 + kc];
        }
        __syncthreads();
        short8v af[MI], bfr[NI];
        #pragma unroll
        for (int mi = 0; mi < MI; mi++)
            af[mi] = *(short8v*)&As[(wr * (BM / 2) + mi * 16 + lr) * 40 + lk * 8];
        #pragma unroll
        for (int ni = 0; ni < NI; ni++)
            bfr[ni] = *(short8v*)&Bs[(wc * (BN / 2) + ni * 16 + lr) * 40 + lk * 8];
        #pragma unroll
        for (int mi = 0; mi < MI; mi++)
            #pragma unroll
            for (int ni = 0; ni < NI; ni++)
                acc[mi][ni] = __builtin_amdgcn_mfma_f32_16x16x32_bf16(
                    af[mi], bfr[ni], acc[mi][ni], 0, 0, 0);
        __syncthreads();
    }

    #pragma unroll
    for (int mi = 0; mi < MI; mi++) {
        #pragma unroll
        for (int ni = 0; ni < NI; ni++) {
            int col = bn + wc * (BN / 2) + ni * 16 + lr;
            float bv = bias ? bias[col] : 0.f;
            #pragma unroll
            for (int j = 0; j < 4; j++) {
                int row = bm + wr * (BM / 2) + mi * 16 + lk * 4 + j;
                float v = acc[mi][ni][j] + bv;
                if (rowbias) v += rowbias[(size_t)(row % LTOK) * N + col];
                if (act == 1) v = (v > 20.f) ? v : logf(1.f + __expf(v));
                if (mode == 0) {
                    Cf[(size_t)row * N + col] = v;
                } else if (mode == 1) {
                    Cbf[(size_t)row * N + col] = f2bf(v);
                } else {
                    Cf[(size_t)row * N + col] = v;
                    if (col < 32)
                        Cbf[(size_t)row * 32 + col] = (col < DTRANK) ? f2bf(v) : (ushort)0;
                }
            }
        }
    }
}

// ---------------- im2col for patch embed (writes bf16) ----------------
__global__ void im2col_kernel(const float* __restrict__ x, ushort* __restrict__ col)
{
    int idx = blockIdx.x * 256 + threadIdx.x;        // over NTOK*768
    if (idx >= NTOK * 768) return;
    int k = idx % 768;
    int m = idx / 768;
    int b = m / LTOK, l = m % LTOK;
    int ph = l / 14, pw = l % 14;
    int c = k / 256, rr = k % 256;
    int i = rr / 16, j = rr % 16;
    col[idx] = f2bf(x[(((size_t)b * 3 + c) * 224 + ph * 16 + i) * 224 + pw * 16 + j]);
}

// ---------------- fused residual-add + LayerNorm (fp32 + bf16 outputs) -------
__global__ __launch_bounds__(64) void add_ln_kernel(
    float* __restrict__ residual, const float* __restrict__ hidden,
    const float* __restrict__ w, const float* __restrict__ b,
    float* __restrict__ xln, ushort* __restrict__ xln_bf)
{
    const int token = blockIdx.x;
    const int lane  = threadIdx.x;
    const size_t base = (size_t)token * DMODEL;
    float v[6];
    float sum = 0.f;
    #pragma unroll
    for (int i = 0; i < 6; i++) {
        int d = lane + i * 64;
        float r = residual[base + d] + hidden[base + d];
        v[i] = r;
        sum += r;
    }
    #pragma unroll
    for (int off = 32; off > 0; off >>= 1) sum += __shfl_xor(sum, off);
    float mu = sum * (1.f / DMODEL);
    float var = 0.f;
    #pragma unroll
    for (int i = 0; i < 6; i++) { float c = v[i] - mu; var += c * c; }
    #pragma unroll
    for (int off = 32; off > 0; off >>= 1) var += __shfl_xor(var, off);
    var *= (1.f / DMODEL);
    float rstd = rsqrtf(var + EPS);
    #pragma unroll
    for (int i = 0; i < 6; i++) {
        int d = lane + i * 64;
        residual[base + d] = v[i];
        float o = (v[i] - mu) * rstd * w[d] + b[d];
        xln[base + d]    = o;
        xln_bf[base + d] = f2bf(o);
    }
}

// ---------------- depthwise causal conv (k=4) + SiLU (bf16 in, dual out) -----
__global__ __launch_bounds__(256) void conv_silu_kernel(
    const ushort* __restrict__ xz,     // [NTOK,1536] bf16; xc = cols 0..767
    const float* __restrict__ cw,      // [768,4]
    const float* __restrict__ cb,      // [768]
    float* __restrict__ out,           // [NTOK,768] fp32 (scan u)
    ushort* __restrict__ out_bf)       // [NTOK,768] bf16 (x-proj A)
{
    int idx = blockIdx.x * 256 + threadIdx.x;
    if (idx >= NTOK * DINNER) return;
    int e = idx % DINNER;
    int m = idx / DINNER;
    int b = m / LTOK, tpos = m % LTOK;
    float4 w4 = ((const float4*)cw)[e];
    float wv[4] = {w4.x, w4.y, w4.z, w4.w};
    float acc = cb[e];
    #pragma unroll
    for (int tau = 0; tau < DCONV; tau++) {
        int l = tpos - (DCONV - 1) + tau;
        if (l >= 0)
            acc += wv[tau] * bf2f(xz[((size_t)(b * LTOK + l)) * (2 * DINNER) + e]);
    }
    float s = acc / (1.f + __expf(-acc));
    out[idx]    = s;
    out_bf[idx] = f2bf(s);
}

// ---------------- selective scan (thread owns (b,d), 16 states in regs) -----
__global__ __launch_bounds__(64) void scan_kernel(
    const float* __restrict__ delta,   // [NTOK,768]
    const float* __restrict__ u,       // [NTOK,768]
    const float* __restrict__ proj,    // [NTOK,64]  (dt|B|C, padded)
    const ushort* __restrict__ xz,     // [NTOK,1536] bf16 (z = cols 768..1535)
    const float* __restrict__ A_log,   // [768,16]
    const float* __restrict__ Dp,      // [768]
    ushort* __restrict__ y)            // [NTOK,768] bf16
{
    const int b = blockIdx.x;                      // 0..31
    const int d = blockIdx.y * 64 + threadIdx.x;   // 0..767
    float Arow[DSTATE];
    #pragma unroll
    for (int n = 0; n < DSTATE; n++) Arow[n] = -__expf(A_log[(size_t)d * DSTATE + n]);
    const float ddp = Dp[d];
    float h[DSTATE];
    #pragma unroll
    for (int n = 0; n < DSTATE; n++) h[n] = 0.f;

    for (int l = 0; l < LTOK; l++) {
        const size_t row = (size_t)b * LTOK + l;
        const float dt = delta[row * DINNER + d];
        const float ut = u[row * DINNER + d];
        float Bv[DSTATE], Cv[DSTATE];
        const float4* prB = (const float4*)(proj + row * PROJW + DTRANK);
        const float4* prC = (const float4*)(proj + row * PROJW + DTRANK + DSTATE);
        #pragma unroll
        for (int q = 0; q < 4; q++) {
            float4 b4 = prB[q];
            Bv[q*4+0]=b4.x; Bv[q*4+1]=b4.y; Bv[q*4+2]=b4.z; Bv[q*4+3]=b4.w;
            float4 c4 = prC[q];
            Cv[q*4+0]=c4.x; Cv[q*4+1]=c4.y; Cv[q*4+2]=c4.z; Cv[q*4+3]=c4.w;
        }
        const float du = dt * ut;
        float acc = 0.f;
        #pragma unroll
        for (int n = 0; n < DSTATE; n++) {
            h[n] = __expf(dt * Arow[n]) * h[n] + du * Bv[n];
            acc += h[n] * Cv[n];
        }
        float zz = bf2f(xz[row * (2 * DINNER) + DINNER + d]);
        float g  = zz / (1.f + __expf(-zz));
        y[row * DINNER + d] = f2bf((acc + ut * ddp) * g);
    }
}

// ---------------- mean pool over tokens ----------------
__global__ __launch_bounds__(256) void pool_kernel(const float* __restrict__ xln,
                                                   float* __restrict__ pooled)
{
    int idx = blockIdx.x * 256 + threadIdx.x;   // 32*384
    if (idx >= BB * DMODEL) return;
    int b = idx / DMODEL, d = idx % DMODEL;
    float s = 0.f;
    for (int l = 0; l < LTOK; l++) s += xln[((size_t)b * LTOK + l) * DMODEL + d];
    pooled[idx] = s * (1.f / LTOK);
}

// ---------------- classifier head ----------------
__global__ __launch_bounds__(256) void head_kernel(const float* __restrict__ pooled,
                                                   const float* __restrict__ hw,
                                                   const float* __restrict__ hb,
                                                   float* __restrict__ out)
{
    int idx = blockIdx.x * 256 + threadIdx.x;   // 32*1000
    if (idx >= BB * NCLS) return;
    int b = idx / NCLS, n = idx % NCLS;
    float s = hb[n];
    const float* p = pooled + (size_t)b * DMODEL;
    const float* w = hw + (size_t)n * DMODEL;
    for (int k = 0; k < DMODEL; k++) s += p[k] * w[k];
    out[idx] = s;
}

// ---------------- launcher ----------------
extern "C" void kernel_launch(void* const* d_in, const int* in_sizes, int n_in,
                              void* d_out, int out_size, void* d_ws, size_t ws_size,
                              hipStream_t stream)
{
    const float* x       = (const float*)d_in[0];
    const float* patch_w = (const float*)d_in[1];
    const float* patch_b = (const float*)d_in[2];
    const float* pos     = (const float*)d_in[3];
    const float* W_in    = (const float*)d_in[4];
    const float* conv_w  = (const float*)d_in[5];
    const float* conv_b  = (const float*)d_in[6];
    const float* W_xp    = (const float*)d_in[7];
    const float* W_dt    = (const float*)d_in[8];
    const float* b_dt    = (const float*)d_in[9];
    const float* A_log   = (const float*)d_in[10];
    const float* D_p     = (const float*)d_in[11];
    const float* W_out   = (const float*)d_in[12];
    const float* ln_w    = (const float*)d_in[13];
    const float* ln_b    = (const float*)d_in[14];
    const float* normf_w = (const float*)d_in[15];
    const float* normf_b = (const float*)d_in[16];
    const float* head_w  = (const float*)d_in[17];
    const float* head_b  = (const float*)d_in[18];
    float* out = (float*)d_out;

    // ---- fp32 workspace ----
    float* wsf = (float*)d_ws;
    size_t off = 0;
    float* xcv    = wsf + off; off += (size_t)NTOK * DINNER;
    float* proj   = wsf + off; off += (size_t)NTOK * PROJW;
    float* delta  = wsf + off; off += (size_t)NTOK * DINNER;
    float* resid  = wsf + off; off += (size_t)NTOK * DMODEL;
    float* hid    = wsf + off; off += (size_t)NTOK * DMODEL;
    float* xln    = wsf + off; off += (size_t)NTOK * DMODEL;
    float* pooled = wsf + off; off += (size_t)BB * DMODEL;
    // ---- bf16 workspace ----
    ushort* wsu = (ushort*)(wsf + off);
    size_t uoff = 0;
    ushort* Win_bf    = wsu + uoff; uoff += (size_t)24 * 1536 * DMODEL;
    ushort* Wout_bf   = wsu + uoff; uoff += (size_t)24 * DMODEL * DINNER;
    ushort* patchw_bf = wsu + uoff; uoff += (size_t)DMODEL * 768;
    ushort* Wxp_bf    = wsu + uoff; uoff += (size_t)24 * 64 * DINNER;
    ushort* Wdt_bf    = wsu + uoff; uoff += (size_t)24 * DINNER * 32;
    ushort* xln_bf    = wsu + uoff; uoff += (size_t)NTOK * DMODEL;
    ushort* xz_bf     = wsu + uoff; uoff += (size_t)NTOK * 1536;
    ushort* xcv_bf    = wsu + uoff; uoff += (size_t)NTOK * DINNER;
    ushort* dtpad_bf  = wsu + uoff; uoff += (size_t)NTOK * 32;
    ushort* y_bf      = wsu + uoff; uoff += (size_t)NTOK * DINNER;
    ushort* col_bf    = y_bf;   // patch GEMM consumes before scan ever writes

    // ---- weight casts / pads (graph-safe, every call) ----
    cast_bf16_kernel<<<2048, 256, 0, stream>>>(W_in,    Win_bf,    24 * 1536 * DMODEL / 4);
    cast_bf16_kernel<<<2048, 256, 0, stream>>>(W_out,   Wout_bf,   24 * DMODEL * DINNER / 4);
    cast_bf16_kernel<<<256,  256, 0, stream>>>(patch_w, patchw_bf, DMODEL * 768 / 4);
    pad_wxp_kernel<<<(24 * 64 * 768 + 255) / 256, 256, 0, stream>>>(W_xp, Wxp_bf);
    pad_wdt_kernel<<<(24 * 768 * 32 + 255) / 256, 256, 0, stream>>>(W_dt, Wdt_bf);

    hipMemsetAsync(resid, 0, (size_t)NTOK * DMODEL * sizeof(float), stream);

    // patch embed: im2col(bf16) + MFMA GEMM (bias + pos fused)
    im2col_kernel<<<(NTOK * 768 + 255) / 256, 256, 0, stream>>>(x, col_bf);
    gemm_mfma<128,128><<<dim3(NTOK / 128, DMODEL / 128), 256, 0, stream>>>(
        col_bf, patchw_bf, hid, nullptr, DMODEL, 768, patch_b, pos, 0, 0);

    for (int l = 0; l < 24; l++) {
        add_ln_kernel<<<NTOK, 64, 0, stream>>>(resid, hid,
                                               ln_w + (size_t)l * DMODEL,
                                               ln_b + (size_t)l * DMODEL, xln, xln_bf);
        // in-projection -> xz bf16: [6272,384] x [1536,384]^T
        gemm_mfma<128,128><<<dim3(NTOK / 128, 1536 / 128), 256, 0, stream>>>(
            xln_bf, Win_bf + (size_t)l * 1536 * DMODEL, nullptr, xz_bf,
            1536, DMODEL, nullptr, nullptr, 0, 1);
        conv_silu_kernel<<<(NTOK * DINNER + 255) / 256, 256, 0, stream>>>(
            xz_bf, conv_w + (size_t)l * DINNER * DCONV, conv_b + (size_t)l * DINNER,
            xcv, xcv_bf);
        // x-proj -> proj fp32 [6272,64] + dtpad bf16 [6272,32]
        gemm_mfma<64,64><<<dim3(NTOK / 64, 1), 256, 0, stream>>>(
            xcv_bf, Wxp_bf + (size_t)l * 64 * DINNER, proj, dtpad_bf,
            64, DINNER, nullptr, nullptr, 0, 2);
        // dt-proj + softplus -> delta fp32: [6272,32] x [768,32]^T
        gemm_mfma<128,128><<<dim3(NTOK / 128, DINNER / 128), 256, 0, stream>>>(
            dtpad_bf, Wdt_bf + (size_t)l * DINNER * 32, delta, nullptr,
            DINNER, 32, b_dt + (size_t)l * DINNER, nullptr, 1, 0);
        scan_kernel<<<dim3(BB, DINNER / 64), 64, 0, stream>>>(
            delta, xcv, proj, xz_bf,
            A_log + (size_t)l * DINNER * DSTATE, D_p + (size_t)l * DINNER, y_bf);
        // out-projection: [6272,768] x [384,768]^T -> hid fp32
        gemm_mfma<128,128><<<dim3(NTOK / 128, DMODEL / 128), 256, 0, stream>>>(
            y_bf, Wout_bf + (size_t)l * DMODEL * DINNER, hid, nullptr,
            DMODEL, DINNER, nullptr, nullptr, 0, 0);
    }

    add_ln_kernel<<<NTOK, 64, 0, stream>>>(resid, hid, normf_w, normf_b, xln, xln_bf);
    pool_kernel<<<(BB * DMODEL + 255) / 256, 256, 0, stream>>>(xln, pooled);
    head_kernel<<<(BB * NCLS + 255) / 256, 256, 0, stream>>>(pooled, head_w, head_b, out);
}